// Round 4
// baseline (141.314 us; speedup 1.0000x reference)
//
#include <hip/hip_runtime.h>

#define HW   112
#define PH   114            // padded plane dim
#define KK   576
#define PLANE_SH (8 * PH * PH * 64)        // shorts per power plane
#define WB_OFF_SH (3 * PLANE_SH)
#define S_OFF_SH  (WB_OFF_SH + 36864)
// ws_size needed: ~40 MB

typedef __attribute__((ext_vector_type(8))) short s16x8;
typedef __attribute__((ext_vector_type(4))) float f32x4;

__device__ inline unsigned short f2bf(float f) {
    unsigned u = __float_as_uint(f);
    u += 0x7FFF + ((u >> 16) & 1);            // RNE
    return (unsigned short)(u >> 16);
}

// ---- pass 1a: zero the 1-px borders of the three padded planes ----
__global__ void border_kernel(unsigned short* __restrict__ pw) {
    const int bid = blockIdx.x;              // 24 = 3p * 8b
    const int p = bid >> 3, b = bid & 7;
    unsigned short* base = pw + (size_t)p * PLANE_SH + (size_t)b * PH * PH * 64;
    const int t = threadIdx.x;
    const s16x8 z = {0, 0, 0, 0, 0, 0, 0, 0};
    for (int i = 0; i < 15; ++i) {
        const int e = t + i * 256;
        if (e >= 3616) break;                // 452 border px * 8 c-octs
        const int n = e >> 3, c8 = e & 7;
        int x, yy;
        if (n < 114)      { yy = 0;   x = n; }
        else if (n < 228) { yy = 113; x = n - 114; }
        else { const int m2 = n - 228; yy = 1 + (m2 >> 1); x = (m2 & 1) ? 113 : 0; }
        *(s16x8*)&base[(yy * PH + x) * 64 + c8 * 8] = z;
    }
}

// ---- pass 1b: NCHW fp32 -> padded NHWC bf16 planes of v, v^2, v^3 ----
__global__ __launch_bounds__(256) void pow_kernel(const float* __restrict__ img,
                                                  unsigned short* __restrict__ pw) {
    __shared__ __align__(16) unsigned short sA[3 * 112 * 72];   // [p][x][c pad 72]
    const int t = threadIdx.x;
    const int bid = blockIdx.x;              // 896 = 8b * 112y
    const int b = bid / 112, y = bid - b * 112;

    const int c = t & 63, xq0 = t >> 6;
    const float4* src = (const float4*)(img + (((size_t)(b * 64 + c) * HW + y) * HW));
    #pragma unroll
    for (int i = 0; i < 7; ++i) {
        const int xq = xq0 + i * 4;
        const float4 v = src[xq];
        const float vv[4] = {v.x, v.y, v.z, v.w};
        #pragma unroll
        for (int u = 0; u < 4; ++u) {
            const float v1 = vv[u], v2 = v1 * v1, v3 = v2 * v1;
            const int x = xq * 4 + u;
            sA[x * 72 + c]         = f2bf(v1);
            sA[8064 + x * 72 + c]  = f2bf(v2);
            sA[16128 + x * 72 + c] = f2bf(v3);
        }
    }
    __syncthreads();

    for (int i = 0; i < 11; ++i) {
        const int ch = t + i * 256;
        if (ch >= 2688) break;               // 3p * 112x * 8 c-octs
        const int p = ch / 896, r = ch - p * 896;
        const int x = r >> 3, c8 = r & 7;
        const s16x8 val = *(const s16x8*)&sA[p * 8064 + x * 72 + c8 * 8];
        *(s16x8*)&pw[(size_t)p * PLANE_SH + ((size_t)(b * PH + y + 1) * PH + (x + 1)) * 64 + c8 * 8] = val;
    }
}

// ---- pass 1c: weights -> bf16 MFMA-B fragment order + row sums ----
// Wb flat index: (((tap*2 + cc)*4 + nt)*64 + lane)*8 + j
//   k = cc*32 + (lane>>4)*8 + j, n = nt*16 + (lane&15), value = W[n][k*9 + tap]
__global__ void prep_kernel(const float* __restrict__ W,
                            unsigned short* __restrict__ wb,
                            float* __restrict__ S) {
    __shared__ float partial[256];
    const int bid = blockIdx.x, t = threadIdx.x;
    if (bid < 144) {
        const int i   = bid * 256 + t;
        const int j   = i & 7;
        const int l   = (i >> 3) & 63;
        const int nt  = (i >> 9) & 3;
        const int cc  = (i >> 11) & 1;
        const int tap = i >> 12;
        const int c   = cc * 32 + ((l >> 4) << 3) + j;
        const int o   = nt * 16 + (l & 15);
        wb[i] = f2bf(W[o * KK + c * 9 + tap]);
    } else {
        const int o = t >> 2, part = t & 3;
        const float4* row = (const float4*)(W + o * KK) + part * 36;
        float s = 0.f;
        for (int k = 0; k < 36; ++k) { float4 v = row[k]; s += v.x + v.y + v.z + v.w; }
        partial[t] = s;
        __syncthreads();
        if (part == 0) S[o] = partial[t] + partial[t + 1] + partial[t + 2] + partial[t + 3];
    }
}

// ---- pass 2: implicit-GEMM conv, direct global->register fragments, no LDS ----
__global__ __launch_bounds__(256, 2) void conv_main(const unsigned short* __restrict__ pw,
                                                    const unsigned short* __restrict__ wb,
                                                    const float* __restrict__ S,
                                                    float* __restrict__ out) {
    const int t = threadIdx.x, wv = t >> 6, lane = t & 63;
    const int m = lane & 15, q = lane >> 4;

    const int bid = blockIdx.x;       // 784: b = bid&7 (XCD pin)
    const int b = bid & 7;
    const int rr = bid >> 3;          // 0..97 = 14 ty * 7 tx
    const int ty = rr / 7, tx = rr - ty * 7;
    const int Y0 = ty * 8, X0 = tx * 16;   // block: 8 rows x 16 cols; wave wv: rows Y0+2wv+{0,1}

    f32x4 acc[3][2][4];               // [power][at][nt]
    #pragma unroll
    for (int p = 0; p < 3; ++p)
        #pragma unroll
        for (int at = 0; at < 2; ++at)
            #pragma unroll
            for (int nt = 0; nt < 4; ++nt)
                acc[p][at][nt] = (f32x4){0.f, 0.f, 0.f, 0.f};

    // per-lane byte offsets within (plane, batch) for the 4 padded rows this wave touches
    const char* pb = (const char*)(pw + (size_t)b * PH * PH * 64);
    int vofs[4];
    #pragma unroll
    for (int r4 = 0; r4 < 4; ++r4)
        vofs[r4] = ((Y0 + 2 * wv + r4) * PH + X0 + m) * 128 + q * 16;

    #pragma unroll 1
    for (int cc = 0; cc < 2; ++cc) {
        #pragma unroll
        for (int kx = 0; kx < 3; ++kx) {
            // B fragments: 3 ky x 4 nt (L1/L2-resident, shared device-wide)
            s16x8 bf[3][4];
            #pragma unroll
            for (int ky = 0; ky < 3; ++ky) {
                const int tap = ky * 3 + kx;
                #pragma unroll
                for (int nt = 0; nt < 4; ++nt)
                    bf[ky][nt] = *(const s16x8*)&wb[(((tap * 2 + cc) * 4 + nt) * 64 + lane) * 8];
            }
            // A fragments: 4 rows x 3 powers, contiguous 16B each, imm offset kx*128 + cc*64
            s16x8 af[4][3];
            #pragma unroll
            for (int r4 = 0; r4 < 4; ++r4)
                #pragma unroll
                for (int p = 0; p < 3; ++p)
                    af[r4][p] = *(const s16x8*)(pb + (size_t)p * (PLANE_SH * 2)
                                                + vofs[r4] + kx * 128 + cc * 64);
            // 72 MFMA: row r4 = at + ky serves both (at,ky) pairs
            #pragma unroll
            for (int ky = 0; ky < 3; ++ky)
                #pragma unroll
                for (int at = 0; at < 2; ++at)
                    #pragma unroll
                    for (int p = 0; p < 3; ++p)
                        #pragma unroll
                        for (int nt = 0; nt < 4; ++nt)
                            acc[p][at][nt] = __builtin_amdgcn_mfma_f32_16x16x32_bf16(
                                af[at + ky][p], bf[ky][nt], acc[p][at][nt], 0, 0, 0);
        }
    }

    // ---- epilogue: D layout n = lane&15, pixel m = q*4 + reg ----
    #pragma unroll
    for (int nt = 0; nt < 4; ++nt) {
        const int o = nt * 16 + (lane & 15);
        const float Sv = S[o];
        const float fS = -0.000287f / 75.f * Sv;
        const float b1 = 0.8448f   + 0.001309f  * Sv;
        const float b2 = 1.37472f  - 0.0025f    * Sv;
        const float b3 = 1.82784f  - 0.000954f  * Sv;
        const float b4 = 2.97984f  - 0.00734f   * Sv;
        const float b5 = 3.89376f  - 0.01017f   * Sv;
        #pragma unroll
        for (int at = 0; at < 2; ++at) {
            float res[4];
            #pragma unroll
            for (int rg = 0; rg < 4; ++rg) {
                const float u1 = acc[0][at][nt][rg];
                const float u2 = acc[1][at][nt][rg];
                const float u3 = acc[2][at][nt][rg];
                const float f  = fS + 0.00354667f * u1 - 0.00146267f * u2;
                const float g1 = b1 + 0.00619f  * u1 - 0.009f    * u2 + 0.001383f * u3;
                const float g2 = b2 + 0.00303f  * u1 - 0.00484f  * u2 + 0.0175f   * u3;
                const float g3 = b3 + 0.00187f  * u1 + 0.001877f * u2 + 0.01502f  * u3;
                const float g4 = b4 + 0.001117f * u1 + 0.00752f  * u2 + 0.009f    * u3;
                const float g5 = b5 + 0.000426f * u1 + 0.00837f  * u2 + 0.00413f  * u3;
                const float E  = __expf(-10.f * f);
                const float s1 = __builtin_amdgcn_rcpf(1.f + E * 4.4816890703f);
                const float s2 = __builtin_amdgcn_rcpf(1.f + E * 9.9741824548f);
                const float s3 = __builtin_amdgcn_rcpf(1.f + E * 24.5325301971f);
                const float s4 = __builtin_amdgcn_rcpf(1.f + E * 49.4024491055f);
                res[rg] = g1 + s1 * (g2 - g1) + s2 * (g3 - g2) + s3 * (g4 - g3) + s4 * (g5 - g4);
            }
            const int y = Y0 + 2 * wv + at;
            float* op = out + (((size_t)(b * 64 + o)) * HW + y) * HW + X0 + q * 4;
            *(float4*)op = make_float4(res[0], res[1], res[2], res[3]);
        }
    }
}

extern "C" void kernel_launch(void* const* d_in, const int* in_sizes, int n_in,
                              void* d_out, int out_size, void* d_ws, size_t ws_size,
                              hipStream_t stream) {
    const float* img = (const float*)d_in[0];
    const float* w   = (const float*)d_in[1];
    float* outp = (float*)d_out;
    unsigned short* pw = (unsigned short*)d_ws;
    unsigned short* wb = pw + WB_OFF_SH;
    float* S = (float*)(pw + S_OFF_SH);

    hipLaunchKernelGGL(border_kernel, dim3(24),  dim3(256), 0, stream, pw);
    hipLaunchKernelGGL(pow_kernel,    dim3(896), dim3(256), 0, stream, img, pw);
    hipLaunchKernelGGL(prep_kernel,   dim3(145), dim3(256), 0, stream, w, wb, S);
    hipLaunchKernelGGL(conv_main,     dim3(784), dim3(256), 0, stream, pw, wb, S, outp);
}